// Round 5
// baseline (411.725 us; speedup 1.0000x reference)
//
#include <hip/hip_runtime.h>

typedef unsigned short u16;
typedef __attribute__((ext_vector_type(8))) short short8;
typedef __attribute__((ext_vector_type(4))) float float4v;

#define BTH (512*256*128)   // elements per output tensor
#define MASKV (-30000.0f)

__device__ __forceinline__ u16 f2bf(float f){
    union{float f; unsigned i;} v; v.f = f;
    unsigned x = v.i;
    unsigned r = (x + 0x7FFFu + ((x >> 16) & 1u)) >> 16;  // RNE
    return (u16)r;
}
__device__ __forceinline__ void store4bf(u16* dst, float4v v){
    dst[0] = f2bf(v[0]); dst[1] = f2bf(v[1]); dst[2] = f2bf(v[2]); dst[3] = f2bf(v[3]);
}

// ---------------- Kernel 0: f32 weights -> bf16 WT[3][128 n][128 k] in ws; fold C^-0.5 into Wq.
__global__ void wt_kernel(const float* __restrict__ Wq, const float* __restrict__ Wk,
                          const float* __restrict__ Wv, u16* __restrict__ WT){
    int idx = blockIdx.x * 256 + threadIdx.x;   // 0..49151
    int w   = idx >> 14;
    int rem = idx & 16383;
    int n = rem >> 7;
    int k = rem & 127;
    const float* src = (w == 0) ? Wq : (w == 1) ? Wk : Wv;
    float val = src[k * 128 + n];
    if (w == 0) val *= 0.08838834764831845f;    // 128^-0.5
    WT[idx] = f2bf(val);
}

// ---------------- Kernel 1: k,v projection (MFMA), f32 outputs to d_out slots 1,2.
__global__ __launch_bounds__(256) void kv_kernel(const float* __restrict__ x,
                                                 const u16* __restrict__ WT,
                                                 float* __restrict__ dout){
    int row0 = blockIdx.x * 64;
    int tid = threadIdx.x;
    int wave = tid >> 6, lane = tid & 63, lq = lane & 15, quad = lane >> 4;

    // A-frags: bf16(x[row0+mt*16+lq][ks*32+quad*8 ..+8])
    short8 a[4][4];
    #pragma unroll
    for (int mt = 0; mt < 4; mt++)
        #pragma unroll
        for (int ks = 0; ks < 4; ks++){
            const float* px = x + (size_t)(row0 + mt*16 + lq)*128 + ks*32 + quad*8;
            float4v lo = *(const float4v*)px;
            float4v hi = *(const float4v*)(px + 4);
            short8 s;
            #pragma unroll
            for (int j = 0; j < 4; j++){
                s[j]     = (short)f2bf(lo[j]);
                s[j + 4] = (short)f2bf(hi[j]);
            }
            a[mt][ks] = s;
        }

    #pragma unroll
    for (int nt4 = 0; nt4 < 4; nt4++){
        int gn = wave*64 + nt4*16;               // [0,256): 0..127 -> k, 128..255 -> v
        short8 b[4];
        #pragma unroll
        for (int ks = 0; ks < 4; ks++)
            b[ks] = *(const short8*)(WT + (size_t)(128 + gn + lq)*128 + ks*32 + quad*8);
        float* outp = dout + (size_t)(1 + (gn >> 7)) * BTH;
        int h = (gn & 127) + lq;
        #pragma unroll
        for (int mt = 0; mt < 4; mt++){
            float4v c = {0.f, 0.f, 0.f, 0.f};
            #pragma unroll
            for (int ks = 0; ks < 4; ks++)
                c = __builtin_amdgcn_mfma_f32_16x16x32_bf16(a[mt][ks], b[ks], c, 0, 0, 0);
            int rowb = row0 + mt*16 + quad*4;
            #pragma unroll
            for (int r = 0; r < 4; r++)
                outp[(size_t)(rowb + r) * 128 + h] = c[r];
        }
    }
}

// ---------------- Kernel 2: fused q-projection + causal flash attention; f32 out to slot 0.
__global__ __launch_bounds__(256) void attn_kernel(const float* __restrict__ x,
                                                   const u16* __restrict__ WT,
                                                   float* __restrict__ dout){
    const float* kg = dout + (size_t)BTH;
    const float* vg = dout + (size_t)2 * BTH;

    __shared__ u16 ksm[64 * 136];   // x tile (phase 0), then K tiles (bf16)
    __shared__ u16 qsm[64 * 136];   // q tile bf16 [row][h]
    __shared__ u16 vts[128 * 72];   // V tile transposed [h][key]
    __shared__ u16 ps [4 * 16 * 72];// per-wave P buffer [16 rows][64 keys]

    int blk = blockIdx.x;
    int b = blk >> 2, qt = blk & 3;
    int tid = threadIdx.x;
    int wave = tid >> 6, lane = tid & 63, lq = lane & 15, quad = lane >> 4;
    int qrow0 = b * 256 + qt * 64;

    // ---- phase 0: stage x rows (f32 -> bf16) into ksm
    #pragma unroll
    for (int g = 0; g < 8; g++){
        int c2 = g*256 + tid;
        int r = c2 >> 5, f4 = c2 & 31;
        float4v xx = *(const float4v*)(x + (size_t)(qrow0 + r)*128 + f4*4);
        store4bf(ksm + r*136 + f4*4, xx);
    }
    __syncthreads();
    // q = x @ Wq (scale pre-folded). Wave computes its 16 rows, 8 n-tiles; C-layout -> qsm.
    {
        short8 ax[4];
        #pragma unroll
        for (int ks = 0; ks < 4; ks++)
            ax[ks] = *(const short8*)(ksm + (wave*16 + lq)*136 + ks*32 + quad*8);
        #pragma unroll
        for (int nt8 = 0; nt8 < 8; nt8++){
            short8 bq[4];
            #pragma unroll
            for (int ks = 0; ks < 4; ks++)
                bq[ks] = *(const short8*)(WT + (size_t)(nt8*16 + lq)*128 + ks*32 + quad*8);
            float4v c = {0.f, 0.f, 0.f, 0.f};
            #pragma unroll
            for (int ks = 0; ks < 4; ks++)
                c = __builtin_amdgcn_mfma_f32_16x16x32_bf16(ax[ks], bq[ks], c, 0, 0, 0);
            #pragma unroll
            for (int r = 0; r < 4; r++)
                qsm[(wave*16 + quad*4 + r)*136 + nt8*16 + lq] = f2bf(c[r]);
        }
    }
    __syncthreads();
    // q A-frags
    short8 qf[4];
    #pragma unroll
    for (int ks = 0; ks < 4; ks++)
        qf[ks] = *(const short8*)(qsm + (wave*16 + lq)*136 + ks*32 + quad*8);

    float4v oacc[8];
    #pragma unroll
    for (int i = 0; i < 8; i++) oacc[i] = (float4v){0.f, 0.f, 0.f, 0.f};
    float mrun[4] = {MASKV, MASKV, MASKV, MASKV};
    float lrun[4] = {0.f, 0.f, 0.f, 0.f};

    for (int kt = 0; kt <= qt; kt++){
        int krow0 = b * 256 + kt * 64;
        __syncthreads();
        // stage K (f32 -> bf16): ksm[row][h]
        #pragma unroll
        for (int g = 0; g < 8; g++){
            int c2 = g*256 + tid;
            int r = c2 >> 5, f4 = c2 & 31;
            float4v kk = *(const float4v*)(kg + (size_t)(krow0 + r)*128 + f4*4);
            store4bf(ksm + r*136 + f4*4, kk);
        }
        // stage V transposed (f32 -> bf16): vts[h][key]
        #pragma unroll
        for (int g = 0; g < 8; g++){
            int c2 = g*256 + tid;
            int key = c2 >> 5, f4 = c2 & 31;
            float4v vv = *(const float4v*)(vg + (size_t)(krow0 + key)*128 + f4*4);
            #pragma unroll
            for (int j = 0; j < 4; j++)
                vts[(f4*4 + j)*72 + key] = f2bf(vv[j]);
        }
        __syncthreads();

        // S = Q K^T : wave's 16 rows x 64 keys
        float4v s4[4];
        #pragma unroll
        for (int nt = 0; nt < 4; nt++){
            float4v c = {0.f, 0.f, 0.f, 0.f};
            #pragma unroll
            for (int ks = 0; ks < 4; ks++){
                short8 bb = *(const short8*)(ksm + (nt*16 + lq)*136 + ks*32 + quad*8);
                c = __builtin_amdgcn_mfma_f32_16x16x32_bf16(qf[ks], bb, c, 0, 0, 0);
            }
            #pragma unroll
            for (int r = 0; r < 4; r++)
                c[r] = fminf(fmaxf(c[r], MASKV), 30000.0f);   // NaN/inf scrub insurance
            s4[nt] = c;
        }
        // causal mask on diagonal tile
        if (kt == qt){
            #pragma unroll
            for (int nt = 0; nt < 4; nt++)
                #pragma unroll
                for (int r = 0; r < 4; r++){
                    int ci = nt*16 + lq;
                    int ri = wave*16 + quad*4 + r;
                    if (ci > ri) s4[nt][r] = MASKV;
                }
        }
        // online softmax (quad's 16 lanes hold one row's 64 cols)
        float p[4][4];
        #pragma unroll
        for (int r = 0; r < 4; r++){
            float mx = fmaxf(fmaxf(s4[0][r], s4[1][r]), fmaxf(s4[2][r], s4[3][r]));
            mx = fmaxf(mx, __shfl_xor(mx, 1));
            mx = fmaxf(mx, __shfl_xor(mx, 2));
            mx = fmaxf(mx, __shfl_xor(mx, 4));
            mx = fmaxf(mx, __shfl_xor(mx, 8));
            float mnew = fmaxf(mrun[r], mx);
            float alpha = __expf(mrun[r] - mnew);
            float rs = 0.f;
            #pragma unroll
            for (int nt = 0; nt < 4; nt++){
                float pv = __expf(s4[nt][r] - mnew);
                p[nt][r] = pv;
                rs += pv;
            }
            rs += __shfl_xor(rs, 1);
            rs += __shfl_xor(rs, 2);
            rs += __shfl_xor(rs, 4);
            rs += __shfl_xor(rs, 8);
            lrun[r] = lrun[r] * alpha + rs;
            mrun[r] = mnew;
            #pragma unroll
            for (int o = 0; o < 8; o++) oacc[o][r] *= alpha;
        }
        // P: C/D-layout -> LDS -> A-layout
        #pragma unroll
        for (int nt = 0; nt < 4; nt++)
            #pragma unroll
            for (int r = 0; r < 4; r++)
                ps[wave*1152 + (quad*4 + r)*72 + nt*16 + lq] = f2bf(p[nt][r]);
        __syncthreads();   // uniform; orders ps/vts writes vs reads
        // O += P V
        #pragma unroll
        for (int k2 = 0; k2 < 2; k2++){
            short8 pa = *(const short8*)(ps + wave*1152 + lq*72 + k2*32 + quad*8);
            #pragma unroll
            for (int o = 0; o < 8; o++){
                short8 bb = *(const short8*)(vts + (o*16 + lq)*72 + k2*32 + quad*8);
                oacc[o] = __builtin_amdgcn_mfma_f32_16x16x32_bf16(pa, bb, oacc[o], 0, 0, 0);
            }
        }
    }
    // epilogue: out f32
    #pragma unroll
    for (int r = 0; r < 4; r++){
        float inv = 1.0f / lrun[r];
        int row = qrow0 + wave*16 + quad*4 + r;
        #pragma unroll
        for (int o = 0; o < 8; o++)
            dout[(size_t)row * 128 + o*16 + lq] = oacc[o][r] * inv;
    }
}

extern "C" void kernel_launch(void* const* d_in, const int* in_sizes, int n_in,
                              void* d_out, int out_size, void* d_ws, size_t ws_size,
                              hipStream_t stream){
    const float* x  = (const float*)d_in[0];
    const float* Wk = (const float*)d_in[1];
    const float* Wq = (const float*)d_in[2];
    const float* Wv = (const float*)d_in[3];
    float* out = (float*)d_out;
    u16* WT = (u16*)d_ws;   // 96 KB scratch

    wt_kernel  <<<192,  256, 0, stream>>>(Wq, Wk, Wv, WT);
    kv_kernel  <<<2048, 256, 0, stream>>>(x, WT, out);
    attn_kernel<<<2048, 256, 0, stream>>>(x, WT, out);
}